// Round 7
// baseline (3052.412 us; speedup 1.0000x reference)
//
#include <hip/hip_runtime.h>

// DRL4TSP pointer-network decoder, fully fused single persistent kernel.
// R9: LDS-pipe relief. R7 (spill fix) and R8 (barrier/store removal) were
// both nulls -> latency/barrier theories dead. Census: ~300 DS instr per
// wave-step (Phase C 96 wave-uniform ds_read_b128 of sA/sAW/sQP + 120
// shfl-xor swizzles + A/B h-reads) x16 waves = ~4800 DS ops/CU/step
// ~= 35-44k cyc of the CU's single LDS pipe vs 57k measured step time:
// LDS-throughput-bound. Changes (bit-exact FP order preserved):
//  1. Phase C: weights/qprime distributed per-lane in registers (lane l
//     holds h=64ch+l), broadcast via v_readlane (VALU, not LDS) in the
//     k-loop. 96 b128/wave-step -> 1 b32 + 2 b128.
//  2. Phase A/B reduces: xor1/xor2 via DPP quad_perm adds (VALU, exact
//     same pairing), only xor4 remains ds_swizzle. 120 -> 40 DS ops.
//  - Phase A: 8-way K-split (gg=tid>>3, qq=tid&7); thread (gg,qq) owns
//    batch qq's LSTM activation for h=gg. sH double-buffered (no barrier
//    between A and activation). Outputs staged in LDS, bulk flush.
//
// Key algebra (unchanged): with x[b,s] = (static0, static1, load-demand, demand):
//   static_hidden[b,h,s] = W_s[h,:].(x0,x1) + b_s[h]                 (rank-2)
//   base[b,h,s]          = A[h,:].x[b,s] + biasT[h]                  (rank-4)
//   dec@W_ih^T           = G[g,:].(x0,x1)[ptr] + gbias[g]            (rank-2)

#define H 128
#define S 128
#define NBATCH 2048
#define NB 8               // batch elements per block
#define NT 1024            // threads per block (16 waves, 4/SIMD)
#define NBLK (NBATCH / NB) // 256 blocks, 1/CU
#define BS (NBATCH * S)

// h-state LDS layout: quarter-swizzled, stride 36. 8-way 16-float K-slices
// land on 8 distinct bank-quads: conflict-free b128 reads (8-lane broadcast).
#define SHQ 36
#define SHB (4 * SHQ)
#define SHI(bb, h) ((bb) * SHB + (((h) >> 5) * SHQ) + ((h) & 31))
#define QPB 132            // qprime row stride (pad +4, rows 16B-aligned)
#define PADF 12288         // 48 KB pad: raw static total > 80 KB -> 1 WG/CU

__device__ __forceinline__ float dot4f(float4 a, float4 b, float c) {
  return fmaf(a.x, b.x, fmaf(a.y, b.y, fmaf(a.z, b.z, fmaf(a.w, b.w, c))));
}
__device__ __forceinline__ float fast_tanh(float x) {
  // tanh(x) = 1 - 2/(e^{2x}+1); overflow->inf->rcp=0->1, underflow->0->-1 (correct)
  float e = __expf(2.f * x);
  float r = __builtin_amdgcn_rcpf(e + 1.f);
  return fmaf(-2.f, r, 1.f);
}
__device__ __forceinline__ float fast_sig(float x) {
  return __builtin_amdgcn_rcpf(1.f + __expf(-x));
}
// 8-lane sum (groups = 8 consecutive lanes): xor1/xor2 as DPP quad_perm
// (VALU; pairing identical to shfl_xor butterfly -> bit-exact), xor4 swizzle.
__device__ __forceinline__ float qsum8(float a) {
  int t;
  t = __builtin_amdgcn_update_dpp(0, __float_as_int(a), 0xB1, 0xF, 0xF, true); // quad_perm [1,0,3,2]
  a += __int_as_float(t);
  t = __builtin_amdgcn_update_dpp(0, __float_as_int(a), 0x4E, 0xF, 0xF, true); // quad_perm [2,3,0,1]
  a += __int_as_float(t);
  a += __shfl_xor(a, 4);
  return a;
}
// wave-local lane broadcast through SGPR (VALU readlane, not LDS)
__device__ __forceinline__ float bcast(float x, int k) {
  return __int_as_float(__builtin_amdgcn_readlane(__float_as_int(x), k));
}

__global__ __launch_bounds__(NT) __attribute__((amdgpu_waves_per_eu(4, 4)))
void drl4tsp_fused(const float* __restrict__ st, const float* __restrict__ dyn,
                   const float* __restrict__ W_s, const float* __restrict__ b_s,
                   const float* __restrict__ W_ld, const float* __restrict__ b_ld,
                   const float* __restrict__ W_d, const float* __restrict__ b_d,
                   const float* __restrict__ W_ih, const float* __restrict__ b_ih,
                   const float* __restrict__ W_hh, const float* __restrict__ b_hh,
                   const float* __restrict__ W_pd, const float* __restrict__ b_pd,
                   const float* __restrict__ W_pld, const float* __restrict__ b_pld,
                   const float* __restrict__ W_pq, const float* __restrict__ b_pq,
                   const float* __restrict__ W_pr, const float* __restrict__ b_pr,
                   const float* __restrict__ attn_W, const float* __restrict__ mark,
                   float* __restrict__ out)
{
  __shared__ float4 sX[NB][S];       // folded per-(b,s) inputs                16 KB
  __shared__ float4 sA[H];           // attention rank-4 weights                2 KB
  __shared__ alignas(16) float sAW[H];     // attn_W                          0.5 KB
  __shared__ float  sQB[H];          // biasT + b_pq                          0.5 KB
  __shared__ float4 sGT4[4][H];      // gate fold (gt0,gt1,gtb,-) per (g,h)     2 KB
  __shared__ float  sH[2][NB * SHB]; // h-state, double-buffered                9 KB
  __shared__ alignas(16) float sQP[NB * QPB]; // qprime = q + biasT             4 KB
  __shared__ float2 sPart[16][64];   // attn h-half partials per wave           8 KB
  __shared__ float  sOutI[NB][S];    // staged tour_idx                         4 KB
  __shared__ float  sOutL[NB][S];    // staged tour_logp                        4 KB
  __shared__ float  sSelX0[NB];
  __shared__ float  sSelX1[NB];
  __shared__ float  sPad[PADF];      // 48 KB occupancy governor

  const int tid = threadIdx.x;
  const int b0  = blockIdx.x * NB;
  const int gg  = tid >> 3, qq = tid & 7;    // matmul: h-row, 8-way K-split
  const int wv  = tid >> 6, lane = tid & 63; // attention
  const int cb  = wv & 7;                    // attention batch
  const int ch  = wv >> 3;                   // attention h-half (0/1)
  const int hC  = 64 * ch + lane;            // this lane's owned h (broadcast duty)

  // Keep sPad allocated: VOLATILE store behind a runtime-opaque guard;
  // mark[0] == 0 in practice so it never executes.
  if (mark[0] > 1e30f) {
    volatile float* vp = sPad;
    vp[tid] = mark[0];
  }

  // ---------------- one-time fold tables & staging ----------------
  // Gate fold for gate-rows (gg, gg+H, gg+2H, gg+3H), computed by qq==0:
  //   gt0[g],gt1[g] = (W_ih@W_s)[row,0..1];  gtb[g] = (W_ih@b_s + b_ih + b_hh)[row]
  if (qq == 0) {
    #pragma unroll
    for (int g = 0; g < 4; ++g) {
      const int row = gg + g * H;
      const float* wr = W_ih + row * H;
      float g0 = 0.f, g1 = 0.f, gb = 0.f;
      for (int h = 0; h < H; h += 4) {
        float4 w   = *(const float4*)(wr + h);
        float4 s01 = *(const float4*)(W_s + 2 * h);
        float4 s23 = *(const float4*)(W_s + 2 * h + 4);
        float4 bs  = *(const float4*)(b_s + h);
        g0 = fmaf(w.x, s01.x, fmaf(w.y, s01.z, fmaf(w.z, s23.x, fmaf(w.w, s23.z, g0))));
        g1 = fmaf(w.x, s01.y, fmaf(w.y, s01.w, fmaf(w.z, s23.y, fmaf(w.w, s23.w, g1))));
        gb = fmaf(w.x, bs.x,  fmaf(w.y, bs.y,  fmaf(w.z, bs.z,  fmaf(w.w, bs.w,  gb))));
      }
      sGT4[g][gg] = make_float4(g0, g1, gb + b_ih[row] + b_hh[row], 0.f);
    }
  }
  if (tid < H) {
    const int h = tid;
    float a0 = 0.f, a1 = 0.f, a2 = 0.f, a3 = 0.f, bt = 0.f;
    for (int j = 0; j < H; ++j) {
      float pr  = W_pr[h * H + j];
      float pld = W_pld[h * H + j];
      float pd  = W_pd[h * H + j];
      float2 wsv = *(const float2*)(W_s + 2 * j);
      float2 wld = *(const float2*)(W_ld + 2 * j);
      float2 wd  = *(const float2*)(W_d + 2 * j);
      a0 = fmaf(pr, wsv.x, a0);
      a1 = fmaf(pr, wsv.y, a1);
      a2 = fmaf(pld, wld.x + wld.y, a2);
      a3 = fmaf(pd,  wd.x + wd.y,  a3);
      bt += pr * b_s[j] + pld * b_ld[j] + pd * b_d[j];
    }
    sA[h]  = make_float4(a0, a1, a2, a3);
    sAW[h] = attn_W[h];
    sQB[h] = bt + b_pr[h] + b_pld[h] + b_pd[h] + b_pq[h];
  }
  {
    int i = tid;                  // NB*S == NT: exactly one element each
    int bb = i >> 7, s = i & (S - 1);
    int go = (b0 + bb) * 2 * S;
    float x0 = st[go + s];
    float x1 = st[go + S + s];
    float ld = dyn[go + s];
    float dm = dyn[go + S + s];
    sX[bb][s] = make_float4(x0, x1, ld - dm, dm);
  }
  for (int i = tid; i < NB * SHB; i += NT) { sH[0][i] = 0.f; sH[1][i] = 0.f; }
  if (tid < NB) {
    int go = (b0 + tid) * 2 * S;  // dec0 = static_hidden[:,:,0] -> x at s=0
    sSelX0[tid] = st[go + 0];
    sSelX1[tid] = st[go + S + 0];
  }
  if (blockIdx.x == 0 && tid == 0) out[2 * BS] = mark[0];

  // ---- register-resident weights: 8-way K-split slices ----
  float4 rW[4][4];                 // 4 gates x 16-K slice  (64 regs)
  #pragma unroll
  for (int g = 0; g < 4; ++g) {
    const float* wr = W_hh + (gg + g * H) * H + 16 * qq;
    #pragma unroll
    for (int k = 0; k < 4; ++k) rW[g][k] = *(const float4*)(wr + 4 * k);
  }
  float4 rQ[4];                    // W_pq slice            (16 regs)
  {
    const float* wr = W_pq + gg * H + 16 * qq;
    #pragma unroll
    for (int k = 0; k < 4; ++k) rQ[k] = *(const float4*)(wr + 4 * k);
  }
  __syncthreads();

  // ---------------- persistent per-thread setup ----------------
  // 16qq stays inside one 32-float swizzle group: flat per-thread LDS offset.
  const int ofsH = ((qq * 16) >> 5) * SHQ + ((qq * 16) & 31);
  const float qb = sQB[gg];
  // Phase C per-lane distributed weights (step-invariant, read ONCE):
  const float4 rCA = sA[hC];
  const float  rCW = sAW[hC];
  float cS = 0.f;                  // c-state for (batch qq, h gg)

  // ---------------- the 128-step decode scan ----------------
  #pragma unroll 1
  for (int t = 0; t < S; ++t) {
    const int p = t & 1;
    // ---- Phase A: gates = fold(x[ptr]) + h_{t-1} @ W_hh^T ----
    const float x0p = sSelX0[qq], x1p = sSelX1[qq];   // stable since merge(t-1)
    float g4[4] = {0.f, 0.f, 0.f, 0.f};
    #pragma unroll
    for (int bb = 0; bb < NB; ++bb) {
      float a0 = 0.f, a1 = 0.f, a2 = 0.f, a3 = 0.f;
      const float* hp = &sH[1 - p][bb * SHB + ofsH];
      #pragma unroll
      for (int k = 0; k < 4; ++k) {
        float4 hv = *(const float4*)(hp + 4 * k);
        a0 = dot4f(rW[0][k], hv, a0);
        a1 = dot4f(rW[1][k], hv, a1);
        a2 = dot4f(rW[2][k], hv, a2);
        a3 = dot4f(rW[3][k], hv, a3);
      }
      a0 = qsum8(a0);
      a1 = qsum8(a1);
      a2 = qsum8(a2);
      a3 = qsum8(a3);
      if (qq == bb) { g4[0] = a0; g4[1] = a1; g4[2] = a2; g4[3] = a3; }
    }

    // ---- LSTM activation (fused, no barrier): write h_t into buf[p] ----
    {
      float4 t0 = sGT4[0][gg];
      float4 t1 = sGT4[1][gg];
      float4 t2 = sGT4[2][gg];
      float4 t3 = sGT4[3][gg];
      float gi = g4[0] + fmaf(t0.x, x0p, fmaf(t0.y, x1p, t0.z));
      float gf = g4[1] + fmaf(t1.x, x0p, fmaf(t1.y, x1p, t1.z));
      float gc = g4[2] + fmaf(t2.x, x0p, fmaf(t2.y, x1p, t2.z));
      float go = g4[3] + fmaf(t3.x, x0p, fmaf(t3.y, x1p, t3.z));
      cS = fast_sig(gf) * cS + fast_sig(gi) * fast_tanh(gc);
      sH[p][SHI(qq, gg)] = fast_sig(go) * fast_tanh(cS);
    }
    __syncthreads();   // h_t visible to all

    // ---- Phase B: qprime = h_t @ W_pq^T + (b_pq + biasT) ----
    {
      float qval = 0.f;
      #pragma unroll
      for (int bb = 0; bb < NB; ++bb) {
        float qa = 0.f;
        const float* hp = &sH[p][bb * SHB + ofsH];
        #pragma unroll
        for (int k = 0; k < 4; ++k)
          qa = dot4f(rQ[k], *(const float4*)(hp + 4 * k), qa);
        qa = qsum8(qa);
        if (qq == bb) qval = qa + qb;
      }
      sQP[qq * QPB + gg] = qval;
    }
    __syncthreads();

    // ---- Phase C: attention partials over h-half ch, batch cb ----
    // lane covers s = lane and s = lane+64; h in [64*ch, 64*ch+64).
    // Weights broadcast from per-lane registers via readlane (VALU, not LDS);
    // FP order identical to the LDS-read version (h ascending).
    float at0 = 0.f, at1 = 0.f;
    {
      const float4 xA = sX[cb][lane];
      const float4 xB = sX[cb][lane + 64];
      const float  qv = sQP[cb * QPB + hC];   // my h's qprime for batch cb
      #pragma unroll 8
      for (int k = 0; k < 64; ++k) {
        float a0 = bcast(rCA.x, k);
        float a1 = bcast(rCA.y, k);
        float a2 = bcast(rCA.z, k);
        float a3 = bcast(rCA.w, k);
        float aw = bcast(rCW,   k);
        float qk = bcast(qv,    k);
        float h0 = fmaf(a0, xA.x, fmaf(a1, xA.y, fmaf(a2, xA.z, fmaf(a3, xA.w, qk))));
        float h1 = fmaf(a0, xB.x, fmaf(a1, xB.y, fmaf(a2, xB.z, fmaf(a3, xB.w, qk))));
        at0 = fmaf(aw, fast_tanh(h0), at0);
        at1 = fmaf(aw, fast_tanh(h1), at1);
      }
    }
    sPart[wv][lane] = make_float2(at0, at1);
    __syncthreads();

    // ---- merge h-halves + masked softmax + argmax + select (waves 0..7) ----
    if (wv < 8) {
      float2 o = sPart[wv ^ 8][lane];
      at0 += o.x; at1 += o.y;
      // mask2: +10000 for s>=1, +0 for s==0
      float a0v = at0 + ((lane == 0) ? 0.f : 10000.f);
      float a1v = at1 + 10000.f;
      float v; int idx;
      if (a1v > a0v) { v = a1v; idx = lane + 64; } else { v = a0v; idx = lane; }
      #pragma unroll
      for (int m = 1; m < 64; m <<= 1) {         // lexicographic max: first-occurrence argmax
        float ov = __shfl_xor(v, m);
        int   oi = __shfl_xor(idx, m);
        if (ov > v || (ov == v && oi < idx)) { v = ov; idx = oi; }
      }
      float es = __expf(a0v - v) + __expf(a1v - v);  // max prob = 1/sum(exp(a-max))
      #pragma unroll
      for (int m = 1; m < 64; m <<= 1) es += __shfl_xor(es, m);
      if (lane == 0) {
        sOutI[cb][t] = (float)idx;               // staged tour_idx
        sOutL[cb][t] = -__logf(es);              // staged tour_logp
        float4 xv = sX[cb][idx];                 // dec_{t+1} = static_hidden[:,:,idx]
        sSelX0[cb] = xv.x;
        sSelX1[cb] = xv.y;
      }
    }
    __syncthreads();
  }

  // ---------------- bulk output flush (coalesced) ----------------
  {
    int bb = tid >> 7, s = tid & (S - 1);       // NB*S == NT
    const int bg = b0 + bb;
    out[bg * S + s]      = sOutI[bb][s];
    out[BS + bg * S + s] = sOutL[bb][s];
  }
}

extern "C" void kernel_launch(void* const* d_in, const int* in_sizes, int n_in,
                              void* d_out, int out_size, void* d_ws, size_t ws_size,
                              hipStream_t stream) {
  const float* st     = (const float*)d_in[0];
  const float* dyn    = (const float*)d_in[1];
  const float* mark   = (const float*)d_in[2];
  const float* W_s    = (const float*)d_in[3];
  const float* b_s    = (const float*)d_in[4];
  const float* W_ld   = (const float*)d_in[5];
  const float* b_ld   = (const float*)d_in[6];
  const float* W_d    = (const float*)d_in[7];
  const float* b_d    = (const float*)d_in[8];
  const float* W_ih   = (const float*)d_in[9];
  const float* b_ih   = (const float*)d_in[10];
  const float* W_hh   = (const float*)d_in[11];
  const float* b_hh   = (const float*)d_in[12];
  const float* W_pd   = (const float*)d_in[13];
  const float* b_pd   = (const float*)d_in[14];
  const float* W_pld  = (const float*)d_in[15];
  const float* b_pld  = (const float*)d_in[16];
  const float* W_pq   = (const float*)d_in[17];
  const float* b_pq   = (const float*)d_in[18];
  const float* W_pr   = (const float*)d_in[19];
  const float* b_pr   = (const float*)d_in[20];
  const float* attn_W = (const float*)d_in[21];
  float* out = (float*)d_out;

  hipLaunchKernelGGL(drl4tsp_fused, dim3(NBLK), dim3(NT), 0, stream,
                     st, dyn, W_s, b_s, W_ld, b_ld, W_d, b_d, W_ih, b_ih,
                     W_hh, b_hh, W_pd, b_pd, W_pld, b_pld, W_pq, b_pq,
                     W_pr, b_pr, attn_W, mark, out);
}

// Round 11
// 2670.263 us; speedup vs baseline: 1.1431x; 1.1431x over previous
//
#include <hip/hip_runtime.h>

// DRL4TSP pointer-network decoder, fully fused single persistent kernel.
// R13 == R12 resubmitted verbatim: the R12 bench died on infrastructure
// ("MI355X container failed twice") -- kernel never ran. R12 was the
// compile-fix of R11 (FMA2 macro -> inline fma2(); braced-initializer
// commas had split macro args). The experiment is still the R11 A/B:
// keep R10's act->B->(C||A')->merge restructure EXACTLY, express packed
// math via __builtin_elementwise_fma on float2 (compiler-defined
// per-element IEEE FMA) instead of R10's hand VOP3P op_sel asm (prime
// suspect for R10's absmax=122). Pass -> asm was the bug, restructure
// value measured; fail -> restructure is the bug, revert to R8 next.
//  Structure: act(g4,sel) |bar| B(q) |bar| C(attn) || A'(gates t+1) |bar|
//             merge(softmax/argmax/sel) |bar|.  g4=0 prologue (h_{-1}=0);
//             sH single-buffered (C's last read and act's next write are
//             separated by two barriers).
//
// Key algebra (unchanged): with x[b,s] = (static0, static1, load-demand, demand):
//   static_hidden[b,h,s] = W_s[h,:].(x0,x1) + b_s[h]                 (rank-2)
//   base[b,h,s]          = A[h,:].x[b,s] + biasT[h]                  (rank-4)
//   dec@W_ih^T           = G[g,:].(x0,x1)[ptr] + gbias[g]            (rank-2)

#define H 128
#define S 128
#define NBATCH 2048
#define NB 8               // batch elements per block
#define NT 1024            // threads per block (16 waves, 4/SIMD)
#define NBLK (NBATCH / NB) // 256 blocks, 1/CU
#define BS (NBATCH * S)

// h-state LDS layout: quarter-swizzled, stride 36. 8-way 16-float K-slices
// land on 8 distinct bank-quads: conflict-free b128 reads (8-lane broadcast).
#define SHQ 36
#define SHB (4 * SHQ)
#define SHI(bb, h) ((bb) * SHB + (((h) >> 5) * SHQ) + ((h) & 31))
#define QPB 132            // qprime row stride (pad +4, rows 16B-aligned)
#define PADF 12288         // 48 KB pad: raw static LDS > 80 KB -> 1 WG/CU

typedef float v2f __attribute__((ext_vector_type(2)));
typedef float v4f __attribute__((ext_vector_type(4)));

__device__ __forceinline__ v2f fma2(v2f a, v2f b, v2f c) {
  return __builtin_elementwise_fma(a, b, c);
}
__device__ __forceinline__ v2f splat2(float x) { return (v2f){x, x}; }

__device__ __forceinline__ float dot4f(float4 a, float4 b, float c) {
  return fmaf(a.x, b.x, fmaf(a.y, b.y, fmaf(a.z, b.z, fmaf(a.w, b.w, c))));
}
__device__ __forceinline__ float fast_tanh(float x) {
  float e = __expf(2.f * x);
  float r = __builtin_amdgcn_rcpf(e + 1.f);
  return fmaf(-2.f, r, 1.f);
}
__device__ __forceinline__ float fast_sig(float x) {
  return __builtin_amdgcn_rcpf(1.f + __expf(-x));
}
// 8-lane sum: xor1/xor2 as DPP quad_perm adds (VALU), xor4 swizzle.
// (validated in R9: same pairing as shfl_xor butterfly -> bit-exact)
__device__ __forceinline__ float qsum8(float a) {
  int t;
  t = __builtin_amdgcn_update_dpp(0, __float_as_int(a), 0xB1, 0xF, 0xF, true);
  a += __int_as_float(t);
  t = __builtin_amdgcn_update_dpp(0, __float_as_int(a), 0x4E, 0xF, 0xF, true);
  a += __int_as_float(t);
  a += __shfl_xor(a, 4);
  return a;
}

__global__ __launch_bounds__(NT) __attribute__((amdgpu_waves_per_eu(4, 4)))
void drl4tsp_fused(const float* __restrict__ st, const float* __restrict__ dyn,
                   const float* __restrict__ W_s, const float* __restrict__ b_s,
                   const float* __restrict__ W_ld, const float* __restrict__ b_ld,
                   const float* __restrict__ W_d, const float* __restrict__ b_d,
                   const float* __restrict__ W_ih, const float* __restrict__ b_ih,
                   const float* __restrict__ W_hh, const float* __restrict__ b_hh,
                   const float* __restrict__ W_pd, const float* __restrict__ b_pd,
                   const float* __restrict__ W_pld, const float* __restrict__ b_pld,
                   const float* __restrict__ W_pq, const float* __restrict__ b_pq,
                   const float* __restrict__ W_pr, const float* __restrict__ b_pr,
                   const float* __restrict__ attn_W, const float* __restrict__ mark,
                   float* __restrict__ out)
{
  __shared__ float4 sX[NB][S];       // folded per-(b,s) inputs                16 KB
  __shared__ float4 sA[H];           // attention rank-4 weights                2 KB
  __shared__ alignas(16) float sAW[H];     // attn_W                          0.5 KB
  __shared__ float  sQB[H];          // biasT + b_pq                          0.5 KB
  __shared__ float4 sGT4[4][H];      // gate fold (gt0,gt1,gtb,-) per (g,h)     2 KB
  __shared__ float  sH[NB * SHB];    // h-state (single buffer)               4.5 KB
  __shared__ alignas(16) float sQP[NB * QPB]; // qprime = q + biasT             4 KB
  __shared__ float2 sPart[16][64];   // attn h-half partials per wave           8 KB
  __shared__ float  sOutI[NB][S];    // staged tour_idx                         4 KB
  __shared__ float  sOutL[NB][S];    // staged tour_logp                        4 KB
  __shared__ float  sSelX0[NB];
  __shared__ float  sSelX1[NB];
  __shared__ float  sPad[PADF];      // 48 KB occupancy governor

  const int tid = threadIdx.x;
  const int b0  = blockIdx.x * NB;
  const int gg  = tid >> 3, qq = tid & 7;    // matmul: h-row, 8-way K-split
  const int wv  = tid >> 6, lane = tid & 63; // attention
  const int cb  = wv & 7;                    // attention batch
  const int ch  = wv >> 3;                   // attention h-half (0/1)

  // Keep sPad allocated: VOLATILE store behind a runtime-opaque guard;
  // mark[0] == 0 in practice so it never executes.
  if (mark[0] > 1e30f) {
    volatile float* vp = sPad;
    vp[tid] = mark[0];
  }

  // ---------------- one-time fold tables & staging ----------------
  if (qq == 0) {
    #pragma unroll
    for (int g = 0; g < 4; ++g) {
      const int row = gg + g * H;
      const float* wr = W_ih + row * H;
      float g0 = 0.f, g1 = 0.f, gb = 0.f;
      for (int h = 0; h < H; h += 4) {
        float4 w   = *(const float4*)(wr + h);
        float4 s01 = *(const float4*)(W_s + 2 * h);
        float4 s23 = *(const float4*)(W_s + 2 * h + 4);
        float4 bs  = *(const float4*)(b_s + h);
        g0 = fmaf(w.x, s01.x, fmaf(w.y, s01.z, fmaf(w.z, s23.x, fmaf(w.w, s23.z, g0))));
        g1 = fmaf(w.x, s01.y, fmaf(w.y, s01.w, fmaf(w.z, s23.y, fmaf(w.w, s23.w, g1))));
        gb = fmaf(w.x, bs.x,  fmaf(w.y, bs.y,  fmaf(w.z, bs.z,  fmaf(w.w, bs.w,  gb))));
      }
      sGT4[g][gg] = make_float4(g0, g1, gb + b_ih[row] + b_hh[row], 0.f);
    }
  }
  if (tid < H) {
    const int h = tid;
    float a0 = 0.f, a1 = 0.f, a2 = 0.f, a3 = 0.f, bt = 0.f;
    for (int j = 0; j < H; ++j) {
      float pr  = W_pr[h * H + j];
      float pld = W_pld[h * H + j];
      float pd  = W_pd[h * H + j];
      float2 wsv = *(const float2*)(W_s + 2 * j);
      float2 wld = *(const float2*)(W_ld + 2 * j);
      float2 wd  = *(const float2*)(W_d + 2 * j);
      a0 = fmaf(pr, wsv.x, a0);
      a1 = fmaf(pr, wsv.y, a1);
      a2 = fmaf(pld, wld.x + wld.y, a2);
      a3 = fmaf(pd,  wd.x + wd.y,  a3);
      bt += pr * b_s[j] + pld * b_ld[j] + pd * b_d[j];
    }
    sA[h]  = make_float4(a0, a1, a2, a3);
    sAW[h] = attn_W[h];
    sQB[h] = bt + b_pr[h] + b_pld[h] + b_pd[h] + b_pq[h];
  }
  {
    int i = tid;                  // NB*S == NT: exactly one element each
    int bb = i >> 7, s = i & (S - 1);
    int go = (b0 + bb) * 2 * S;
    float x0 = st[go + s];
    float x1 = st[go + S + s];
    float ld = dyn[go + s];
    float dm = dyn[go + S + s];
    sX[bb][s] = make_float4(x0, x1, ld - dm, dm);
  }
  for (int i = tid; i < NB * SHB; i += NT) sH[i] = 0.f;
  if (tid < NB) {
    int go = (b0 + tid) * 2 * S;  // dec0 = static_hidden[:,:,0] -> x at s=0
    sSelX0[tid] = st[go + 0];
    sSelX1[tid] = st[go + S + 0];
  }
  if (blockIdx.x == 0 && tid == 0) out[2 * BS] = mark[0];

  // ---- register-resident weights: gate-PAIR interleaved 16-K slices ----
  v2f rW01[4][4], rW23[4][4];      // {w_i,w_f} and {w_g,w_o} pairs (64 regs)
  #pragma unroll
  for (int k = 0; k < 4; ++k) {
    const int co = 16 * qq + 4 * k;
    float4 w0 = *(const float4*)(W_hh + (gg        ) * H + co);
    float4 w1 = *(const float4*)(W_hh + (gg +     H) * H + co);
    float4 w2 = *(const float4*)(W_hh + (gg + 2 * H) * H + co);
    float4 w3 = *(const float4*)(W_hh + (gg + 3 * H) * H + co);
    rW01[k][0] = (v2f){w0.x, w1.x}; rW01[k][1] = (v2f){w0.y, w1.y};
    rW01[k][2] = (v2f){w0.z, w1.z}; rW01[k][3] = (v2f){w0.w, w1.w};
    rW23[k][0] = (v2f){w2.x, w3.x}; rW23[k][1] = (v2f){w2.y, w3.y};
    rW23[k][2] = (v2f){w2.z, w3.z}; rW23[k][3] = (v2f){w2.w, w3.w};
  }
  float4 rQ[4];                    // W_pq slice (16 regs)
  {
    const float* wr = W_pq + gg * H + 16 * qq;
    #pragma unroll
    for (int k = 0; k < 4; ++k) rQ[k] = *(const float4*)(wr + 4 * k);
  }
  __syncthreads();

  // ---------------- persistent per-thread setup ----------------
  const int ofsH = ((qq * 16) >> 5) * SHQ + ((qq * 16) & 31);
  const float qb = sQB[gg];
  // Phase C x-pairs: {xA.c, xB.c} packed once (step-invariant)
  v2f xx2, xy2, xz2, xw2;
  {
    float4 xA = sX[cb][lane];
    float4 xB = sX[cb][lane + 64];
    xx2 = (v2f){xA.x, xB.x}; xy2 = (v2f){xA.y, xB.y};
    xz2 = (v2f){xA.z, xB.z}; xw2 = (v2f){xA.w, xB.w};
  }
  float cS = 0.f;                      // c-state for (batch qq, h gg)
  float g4[4] = {0.f, 0.f, 0.f, 0.f};  // W_hh@h part of gates; h_{-1}=0 -> 0

  // ---------------- the 128-step decode scan ----------------
  #pragma unroll 1
  for (int t = 0; t < S; ++t) {
    // ---- act: gates = g4 + fold(x[sel]); h_t -> sH ----
    {
      const float x0p = sSelX0[qq], x1p = sSelX1[qq];
      float4 t0 = sGT4[0][gg];
      float4 t1 = sGT4[1][gg];
      float4 t2 = sGT4[2][gg];
      float4 t3 = sGT4[3][gg];
      float gi = g4[0] + fmaf(t0.x, x0p, fmaf(t0.y, x1p, t0.z));
      float gf = g4[1] + fmaf(t1.x, x0p, fmaf(t1.y, x1p, t1.z));
      float gc = g4[2] + fmaf(t2.x, x0p, fmaf(t2.y, x1p, t2.z));
      float go = g4[3] + fmaf(t3.x, x0p, fmaf(t3.y, x1p, t3.z));
      cS = fast_sig(gf) * cS + fast_sig(gi) * fast_tanh(gc);
      sH[SHI(qq, gg)] = fast_sig(go) * fast_tanh(cS);
    }
    __syncthreads();   // h_t visible

    // ---- Phase B: qprime = h_t @ W_pq^T + (b_pq + biasT) ----
    {
      float qval = 0.f;
      #pragma unroll
      for (int bb = 0; bb < NB; ++bb) {
        float qa = 0.f;
        const float* hp = &sH[bb * SHB + ofsH];
        #pragma unroll
        for (int k = 0; k < 4; ++k)
          qa = dot4f(rQ[k], *(const float4*)(hp + 4 * k), qa);
        qa = qsum8(qa);
        if (qq == bb) qval = qa + qb;
      }
      sQP[qq * QPB + gg] = qval;
    }
    __syncthreads();

    // ---- Phase C (attention, v2f s/s+64) || A' (gates for t+1) ----
    v2f at2 = {0.f, 0.f};
    #pragma unroll 1
    for (int jj = 0; jj < 8; ++jj) {
      // A' slice: batch jj, this thread's 16-K gate-pair dots.
      // Order matches dot4f: per k, j=3 down to j=0; k ascending.
      v2f a01 = {0.f, 0.f}, a23 = {0.f, 0.f};
      {
        const float* hp = &sH[jj * SHB + ofsH];
        #pragma unroll
        for (int k = 0; k < 4; ++k) {
          v4f hv = *(const v4f*)(hp + 4 * k);
          v2f hx = splat2(hv.x), hy = splat2(hv.y);
          v2f hz = splat2(hv.z), hw = splat2(hv.w);
          a01 = fma2(rW01[k][3], hw, a01);
          a01 = fma2(rW01[k][2], hz, a01);
          a01 = fma2(rW01[k][1], hy, a01);
          a01 = fma2(rW01[k][0], hx, a01);
          a23 = fma2(rW23[k][3], hw, a23);
          a23 = fma2(rW23[k][2], hz, a23);
          a23 = fma2(rW23[k][1], hy, a23);
          a23 = fma2(rW23[k][0], hx, a23);
        }
      }
      // C slice: 8 h values (ascending h overall -> same accumulation order
      // as R8; both lanes of each v2f op are independent IEEE FMAs).
      {
        const int hbase = 64 * ch + 8 * jj;
        #pragma unroll
        for (int hh = 0; hh < 8; ++hh) {
          const int h = hbase + hh;
          float4 a  = sA[h];
          float  aw = sAW[h];
          float  q  = sQP[cb * QPB + h];
          v2f acc = splat2(q);
          acc = fma2(splat2(a.w), xw2, acc);
          acc = fma2(splat2(a.z), xz2, acc);
          acc = fma2(splat2(a.y), xy2, acc);
          acc = fma2(splat2(a.x), xx2, acc);
          v2f tt = acc + acc;                 // 2x (exact)
          v2f e  = (v2f){__expf(tt.x), __expf(tt.y)};
          v2f r  = (v2f){__builtin_amdgcn_rcpf(e.x + 1.f),
                         __builtin_amdgcn_rcpf(e.y + 1.f)};
          v2f th = fma2(splat2(-2.f), r, splat2(1.f));
          at2 = fma2(splat2(aw), th, at2);
        }
      }
      // A' reduce + keep own batch
      {
        float r0 = qsum8(a01.x);
        float r1 = qsum8(a01.y);
        float r2 = qsum8(a23.x);
        float r3 = qsum8(a23.y);
        if (qq == jj) { g4[0] = r0; g4[1] = r1; g4[2] = r2; g4[3] = r3; }
      }
    }
    sPart[wv][lane] = make_float2(at2.x, at2.y);
    __syncthreads();

    // ---- merge h-halves + masked softmax + argmax + select (waves 0..7) ----
    if (wv < 8) {
      float at0 = at2.x, at1 = at2.y;
      float2 o = sPart[wv ^ 8][lane];
      at0 += o.x; at1 += o.y;
      float a0v = at0 + ((lane == 0) ? 0.f : 10000.f);
      float a1v = at1 + 10000.f;
      float v; int idx;
      if (a1v > a0v) { v = a1v; idx = lane + 64; } else { v = a0v; idx = lane; }
      #pragma unroll
      for (int m = 1; m < 64; m <<= 1) {         // lexicographic max
        float ov = __shfl_xor(v, m);
        int   oi = __shfl_xor(idx, m);
        if (ov > v || (ov == v && oi < idx)) { v = ov; idx = oi; }
      }
      float es = __expf(a0v - v) + __expf(a1v - v);
      #pragma unroll
      for (int m = 1; m < 64; m <<= 1) es += __shfl_xor(es, m);
      if (lane == 0) {
        sOutI[cb][t] = (float)idx;               // staged tour_idx
        sOutL[cb][t] = -__logf(es);              // staged tour_logp
        float4 xv = sX[cb][idx];                 // dec_{t+1}
        sSelX0[cb] = xv.x;
        sSelX1[cb] = xv.y;
      }
    }
    __syncthreads();
  }

  // ---------------- bulk output flush (coalesced) ----------------
  {
    int bb = tid >> 7, s = tid & (S - 1);       // NB*S == NT
    const int bg = b0 + bb;
    out[bg * S + s]      = sOutI[bb][s];
    out[BS + bg * S + s] = sOutL[bb][s];
  }
}

extern "C" void kernel_launch(void* const* d_in, const int* in_sizes, int n_in,
                              void* d_out, int out_size, void* d_ws, size_t ws_size,
                              hipStream_t stream) {
  const float* st     = (const float*)d_in[0];
  const float* dyn    = (const float*)d_in[1];
  const float* mark   = (const float*)d_in[2];
  const float* W_s    = (const float*)d_in[3];
  const float* b_s    = (const float*)d_in[4];
  const float* W_ld   = (const float*)d_in[5];
  const float* b_ld   = (const float*)d_in[6];
  const float* W_d    = (const float*)d_in[7];
  const float* b_d    = (const float*)d_in[8];
  const float* W_ih   = (const float*)d_in[9];
  const float* b_ih   = (const float*)d_in[10];
  const float* W_hh   = (const float*)d_in[11];
  const float* b_hh   = (const float*)d_in[12];
  const float* W_pd   = (const float*)d_in[13];
  const float* b_pd   = (const float*)d_in[14];
  const float* W_pld  = (const float*)d_in[15];
  const float* b_pld  = (const float*)d_in[16];
  const float* W_pq   = (const float*)d_in[17];
  const float* b_pq   = (const float*)d_in[18];
  const float* W_pr   = (const float*)d_in[19];
  const float* b_pr   = (const float*)d_in[20];
  const float* attn_W = (const float*)d_in[21];
  float* out = (float*)d_out;

  hipLaunchKernelGGL(drl4tsp_fused, dim3(NBLK), dim3(NT), 0, stream,
                     st, dyn, W_s, b_s, W_ld, b_ld, W_d, b_d, W_ih, b_ih,
                     W_hh, b_hh, W_pd, b_pd, W_pld, b_pld, W_pq, b_pq,
                     W_pr, b_pr, attn_W, mark, out);
}

// Round 12
// 2313.280 us; speedup vs baseline: 1.3195x; 1.1543x over previous
//
#include <hip/hip_runtime.h>

// DRL4TSP pointer-network decoder, fully fused single persistent kernel.
// R14: fix R13's register-peak spill. R13 passed (2990 steady, +2.3% --
// R10's hand VOP3P op_sel asm was the correctness bug, restructure fine)
// but WRITE_SIZE blew up 18->210 MB: interleaving A' into C's loop body
// made both phases' temps co-live (~150 regs peak > 128) -> loop-carried
// scratch spill whose reloads ate the packing gains.
// Changes vs R13:
//  1. A' de-interleaved from C and moved to the MERGE region:
//     act |bar| B |bar| C |bar| (merge[wv<8] || A'[all]) |bar|.
//     A' reads only sH (stable until next act); merge writes only
//     sOutI/L + sSelX (A' doesn't read) -> no hazard. Bonus: merge's
//     serial ~100 ops now overlap A' instead of idling 8 waves.
//  2. A' back to R8's proven scalar float4 dot4f + qsum8 (rW row layout);
//     C keeps R13's packed v2f math. Peak live regs per region < 128.
//
// Key algebra (unchanged): with x[b,s] = (static0, static1, load-demand, demand):
//   static_hidden[b,h,s] = W_s[h,:].(x0,x1) + b_s[h]                 (rank-2)
//   base[b,h,s]          = A[h,:].x[b,s] + biasT[h]                  (rank-4)
//   dec@W_ih^T           = G[g,:].(x0,x1)[ptr] + gbias[g]            (rank-2)

#define H 128
#define S 128
#define NBATCH 2048
#define NB 8               // batch elements per block
#define NT 1024            // threads per block (16 waves, 4/SIMD)
#define NBLK (NBATCH / NB) // 256 blocks, 1/CU
#define BS (NBATCH * S)

// h-state LDS layout: quarter-swizzled, stride 36. 8-way 16-float K-slices
// land on 8 distinct bank-quads: conflict-free b128 reads (8-lane broadcast).
#define SHQ 36
#define SHB (4 * SHQ)
#define SHI(bb, h) ((bb) * SHB + (((h) >> 5) * SHQ) + ((h) & 31))
#define QPB 132            // qprime row stride (pad +4, rows 16B-aligned)
#define PADF 12288         // 48 KB pad: raw static LDS > 80 KB -> 1 WG/CU

typedef float v2f __attribute__((ext_vector_type(2)));
typedef float v4f __attribute__((ext_vector_type(4)));

__device__ __forceinline__ v2f fma2(v2f a, v2f b, v2f c) {
  return __builtin_elementwise_fma(a, b, c);
}
__device__ __forceinline__ v2f splat2(float x) { return (v2f){x, x}; }

__device__ __forceinline__ float dot4f(float4 a, float4 b, float c) {
  return fmaf(a.x, b.x, fmaf(a.y, b.y, fmaf(a.z, b.z, fmaf(a.w, b.w, c))));
}
__device__ __forceinline__ float fast_tanh(float x) {
  float e = __expf(2.f * x);
  float r = __builtin_amdgcn_rcpf(e + 1.f);
  return fmaf(-2.f, r, 1.f);
}
__device__ __forceinline__ float fast_sig(float x) {
  return __builtin_amdgcn_rcpf(1.f + __expf(-x));
}
// 8-lane sum: xor1/xor2 as DPP quad_perm adds (VALU), xor4 swizzle.
// (validated in R9/R13: same pairing as shfl_xor butterfly -> bit-exact)
__device__ __forceinline__ float qsum8(float a) {
  int t;
  t = __builtin_amdgcn_update_dpp(0, __float_as_int(a), 0xB1, 0xF, 0xF, true);
  a += __int_as_float(t);
  t = __builtin_amdgcn_update_dpp(0, __float_as_int(a), 0x4E, 0xF, 0xF, true);
  a += __int_as_float(t);
  a += __shfl_xor(a, 4);
  return a;
}

__global__ __launch_bounds__(NT) __attribute__((amdgpu_waves_per_eu(4, 4)))
void drl4tsp_fused(const float* __restrict__ st, const float* __restrict__ dyn,
                   const float* __restrict__ W_s, const float* __restrict__ b_s,
                   const float* __restrict__ W_ld, const float* __restrict__ b_ld,
                   const float* __restrict__ W_d, const float* __restrict__ b_d,
                   const float* __restrict__ W_ih, const float* __restrict__ b_ih,
                   const float* __restrict__ W_hh, const float* __restrict__ b_hh,
                   const float* __restrict__ W_pd, const float* __restrict__ b_pd,
                   const float* __restrict__ W_pld, const float* __restrict__ b_pld,
                   const float* __restrict__ W_pq, const float* __restrict__ b_pq,
                   const float* __restrict__ W_pr, const float* __restrict__ b_pr,
                   const float* __restrict__ attn_W, const float* __restrict__ mark,
                   float* __restrict__ out)
{
  __shared__ float4 sX[NB][S];       // folded per-(b,s) inputs                16 KB
  __shared__ float4 sA[H];           // attention rank-4 weights                2 KB
  __shared__ alignas(16) float sAW[H];     // attn_W                          0.5 KB
  __shared__ float  sQB[H];          // biasT + b_pq                          0.5 KB
  __shared__ float4 sGT4[4][H];      // gate fold (gt0,gt1,gtb,-) per (g,h)     2 KB
  __shared__ float  sH[NB * SHB];    // h-state (single buffer)               4.5 KB
  __shared__ alignas(16) float sQP[NB * QPB]; // qprime = q + biasT             4 KB
  __shared__ float2 sPart[16][64];   // attn h-half partials per wave           8 KB
  __shared__ float  sOutI[NB][S];    // staged tour_idx                         4 KB
  __shared__ float  sOutL[NB][S];    // staged tour_logp                        4 KB
  __shared__ float  sSelX0[NB];
  __shared__ float  sSelX1[NB];
  __shared__ float  sPad[PADF];      // 48 KB occupancy governor

  const int tid = threadIdx.x;
  const int b0  = blockIdx.x * NB;
  const int gg  = tid >> 3, qq = tid & 7;    // matmul: h-row, 8-way K-split
  const int wv  = tid >> 6, lane = tid & 63; // attention
  const int cb  = wv & 7;                    // attention batch
  const int ch  = wv >> 3;                   // attention h-half (0/1)

  // Keep sPad allocated: VOLATILE store behind a runtime-opaque guard;
  // mark[0] == 0 in practice so it never executes.
  if (mark[0] > 1e30f) {
    volatile float* vp = sPad;
    vp[tid] = mark[0];
  }

  // ---------------- one-time fold tables & staging ----------------
  if (qq == 0) {
    #pragma unroll
    for (int g = 0; g < 4; ++g) {
      const int row = gg + g * H;
      const float* wr = W_ih + row * H;
      float g0 = 0.f, g1 = 0.f, gb = 0.f;
      for (int h = 0; h < H; h += 4) {
        float4 w   = *(const float4*)(wr + h);
        float4 s01 = *(const float4*)(W_s + 2 * h);
        float4 s23 = *(const float4*)(W_s + 2 * h + 4);
        float4 bs  = *(const float4*)(b_s + h);
        g0 = fmaf(w.x, s01.x, fmaf(w.y, s01.z, fmaf(w.z, s23.x, fmaf(w.w, s23.z, g0))));
        g1 = fmaf(w.x, s01.y, fmaf(w.y, s01.w, fmaf(w.z, s23.y, fmaf(w.w, s23.w, g1))));
        gb = fmaf(w.x, bs.x,  fmaf(w.y, bs.y,  fmaf(w.z, bs.z,  fmaf(w.w, bs.w,  gb))));
      }
      sGT4[g][gg] = make_float4(g0, g1, gb + b_ih[row] + b_hh[row], 0.f);
    }
  }
  if (tid < H) {
    const int h = tid;
    float a0 = 0.f, a1 = 0.f, a2 = 0.f, a3 = 0.f, bt = 0.f;
    for (int j = 0; j < H; ++j) {
      float pr  = W_pr[h * H + j];
      float pld = W_pld[h * H + j];
      float pd  = W_pd[h * H + j];
      float2 wsv = *(const float2*)(W_s + 2 * j);
      float2 wld = *(const float2*)(W_ld + 2 * j);
      float2 wd  = *(const float2*)(W_d + 2 * j);
      a0 = fmaf(pr, wsv.x, a0);
      a1 = fmaf(pr, wsv.y, a1);
      a2 = fmaf(pld, wld.x + wld.y, a2);
      a3 = fmaf(pd,  wd.x + wd.y,  a3);
      bt += pr * b_s[j] + pld * b_ld[j] + pd * b_d[j];
    }
    sA[h]  = make_float4(a0, a1, a2, a3);
    sAW[h] = attn_W[h];
    sQB[h] = bt + b_pr[h] + b_pld[h] + b_pd[h] + b_pq[h];
  }
  {
    int i = tid;                  // NB*S == NT: exactly one element each
    int bb = i >> 7, s = i & (S - 1);
    int go = (b0 + bb) * 2 * S;
    float x0 = st[go + s];
    float x1 = st[go + S + s];
    float ld = dyn[go + s];
    float dm = dyn[go + S + s];
    sX[bb][s] = make_float4(x0, x1, ld - dm, dm);
  }
  for (int i = tid; i < NB * SHB; i += NT) sH[i] = 0.f;
  if (tid < NB) {
    int go = (b0 + tid) * 2 * S;  // dec0 = static_hidden[:,:,0] -> x at s=0
    sSelX0[tid] = st[go + 0];
    sSelX1[tid] = st[go + S + 0];
  }
  if (blockIdx.x == 0 && tid == 0) out[2 * BS] = mark[0];

  // ---- register-resident weights: 8-way K-split slices (R8 row layout) ----
  float4 rW[4][4];                 // 4 gates x 16-K slice  (64 regs)
  #pragma unroll
  for (int g = 0; g < 4; ++g) {
    const float* wr = W_hh + (gg + g * H) * H + 16 * qq;
    #pragma unroll
    for (int k = 0; k < 4; ++k) rW[g][k] = *(const float4*)(wr + 4 * k);
  }
  float4 rQ[4];                    // W_pq slice (16 regs)
  {
    const float* wr = W_pq + gg * H + 16 * qq;
    #pragma unroll
    for (int k = 0; k < 4; ++k) rQ[k] = *(const float4*)(wr + 4 * k);
  }
  __syncthreads();

  // ---------------- persistent per-thread setup ----------------
  const int ofsH = ((qq * 16) >> 5) * SHQ + ((qq * 16) & 31);
  const float qb = sQB[gg];
  // Phase C x-pairs: {xA.c, xB.c} packed once (step-invariant)
  v2f xx2, xy2, xz2, xw2;
  {
    float4 xA = sX[cb][lane];
    float4 xB = sX[cb][lane + 64];
    xx2 = (v2f){xA.x, xB.x}; xy2 = (v2f){xA.y, xB.y};
    xz2 = (v2f){xA.z, xB.z}; xw2 = (v2f){xA.w, xB.w};
  }
  float cS = 0.f;                      // c-state for (batch qq, h gg)
  float g4[4] = {0.f, 0.f, 0.f, 0.f};  // W_hh@h part of gates; h_{-1}=0 -> 0

  // ---------------- the 128-step decode scan ----------------
  // act |bar| B |bar| C |bar| (merge[wv<8] || A'[all]) |bar|
  #pragma unroll 1
  for (int t = 0; t < S; ++t) {
    // ---- act: gates = g4 + fold(x[sel]); h_t -> sH ----
    {
      const float x0p = sSelX0[qq], x1p = sSelX1[qq];
      float4 t0 = sGT4[0][gg];
      float4 t1 = sGT4[1][gg];
      float4 t2 = sGT4[2][gg];
      float4 t3 = sGT4[3][gg];
      float gi = g4[0] + fmaf(t0.x, x0p, fmaf(t0.y, x1p, t0.z));
      float gf = g4[1] + fmaf(t1.x, x0p, fmaf(t1.y, x1p, t1.z));
      float gc = g4[2] + fmaf(t2.x, x0p, fmaf(t2.y, x1p, t2.z));
      float go = g4[3] + fmaf(t3.x, x0p, fmaf(t3.y, x1p, t3.z));
      cS = fast_sig(gf) * cS + fast_sig(gi) * fast_tanh(gc);
      sH[SHI(qq, gg)] = fast_sig(go) * fast_tanh(cS);
    }
    __syncthreads();   // h_t visible

    // ---- Phase B: qprime = h_t @ W_pq^T + (b_pq + biasT) ----
    {
      float qval = 0.f;
      #pragma unroll
      for (int bb = 0; bb < NB; ++bb) {
        float qa = 0.f;
        const float* hp = &sH[bb * SHB + ofsH];
        #pragma unroll
        for (int k = 0; k < 4; ++k)
          qa = dot4f(rQ[k], *(const float4*)(hp + 4 * k), qa);
        qa = qsum8(qa);
        if (qq == bb) qval = qa + qb;
      }
      sQP[qq * QPB + gg] = qval;
    }
    __syncthreads();

    // ---- Phase C: attention (packed s/s+64), h in [64ch, 64ch+64) ----
    v2f at2 = {0.f, 0.f};
    {
      const int hbase = 64 * ch;
      #pragma unroll 8
      for (int hh = 0; hh < 64; ++hh) {
        const int h = hbase + hh;
        float4 a  = sA[h];
        float  aw = sAW[h];
        float  q  = sQP[cb * QPB + h];
        v2f acc = splat2(q);
        acc = fma2(splat2(a.w), xw2, acc);
        acc = fma2(splat2(a.z), xz2, acc);
        acc = fma2(splat2(a.y), xy2, acc);
        acc = fma2(splat2(a.x), xx2, acc);
        v2f tt = acc + acc;                 // 2x (exact)
        v2f e  = (v2f){__expf(tt.x), __expf(tt.y)};
        v2f r  = (v2f){__builtin_amdgcn_rcpf(e.x + 1.f),
                       __builtin_amdgcn_rcpf(e.y + 1.f)};
        v2f th = fma2(splat2(-2.f), r, splat2(1.f));
        at2 = fma2(splat2(aw), th, at2);
      }
    }
    sPart[wv][lane] = make_float2(at2.x, at2.y);
    __syncthreads();

    // ---- merge (waves 0..7) || A' (all threads: gates for t+1) ----
    if (wv < 8) {
      float at0 = at2.x, at1 = at2.y;
      float2 o = sPart[wv ^ 8][lane];
      at0 += o.x; at1 += o.y;
      float a0v = at0 + ((lane == 0) ? 0.f : 10000.f);
      float a1v = at1 + 10000.f;
      float v; int idx;
      if (a1v > a0v) { v = a1v; idx = lane + 64; } else { v = a0v; idx = lane; }
      #pragma unroll
      for (int m = 1; m < 64; m <<= 1) {         // lexicographic max
        float ov = __shfl_xor(v, m);
        int   oi = __shfl_xor(idx, m);
        if (ov > v || (ov == v && oi < idx)) { v = ov; idx = oi; }
      }
      float es = __expf(a0v - v) + __expf(a1v - v);
      #pragma unroll
      for (int m = 1; m < 64; m <<= 1) es += __shfl_xor(es, m);
      if (lane == 0) {
        sOutI[cb][t] = (float)idx;               // staged tour_idx
        sOutL[cb][t] = -__logf(es);              // staged tour_logp
        float4 xv = sX[cb][idx];                 // dec_{t+1}
        sSelX0[cb] = xv.x;
        sSelX1[cb] = xv.y;
      }
    }
    // A': next step's W_hh @ h_t (sH stable until next act, 1 barrier away)
    {
      #pragma unroll
      for (int bb = 0; bb < NB; ++bb) {
        float a0 = 0.f, a1 = 0.f, a2 = 0.f, a3 = 0.f;
        const float* hp = &sH[bb * SHB + ofsH];
        #pragma unroll
        for (int k = 0; k < 4; ++k) {
          float4 hv = *(const float4*)(hp + 4 * k);
          a0 = dot4f(rW[0][k], hv, a0);
          a1 = dot4f(rW[1][k], hv, a1);
          a2 = dot4f(rW[2][k], hv, a2);
          a3 = dot4f(rW[3][k], hv, a3);
        }
        a0 = qsum8(a0);
        a1 = qsum8(a1);
        a2 = qsum8(a2);
        a3 = qsum8(a3);
        if (qq == bb) { g4[0] = a0; g4[1] = a1; g4[2] = a2; g4[3] = a3; }
      }
    }
    __syncthreads();
  }

  // ---------------- bulk output flush (coalesced) ----------------
  {
    int bb = tid >> 7, s = tid & (S - 1);       // NB*S == NT
    const int bg = b0 + bb;
    out[bg * S + s]      = sOutI[bb][s];
    out[BS + bg * S + s] = sOutL[bb][s];
  }
}

extern "C" void kernel_launch(void* const* d_in, const int* in_sizes, int n_in,
                              void* d_out, int out_size, void* d_ws, size_t ws_size,
                              hipStream_t stream) {
  const float* st     = (const float*)d_in[0];
  const float* dyn    = (const float*)d_in[1];
  const float* mark   = (const float*)d_in[2];
  const float* W_s    = (const float*)d_in[3];
  const float* b_s    = (const float*)d_in[4];
  const float* W_ld   = (const float*)d_in[5];
  const float* b_ld   = (const float*)d_in[6];
  const float* W_d    = (const float*)d_in[7];
  const float* b_d    = (const float*)d_in[8];
  const float* W_ih   = (const float*)d_in[9];
  const float* b_ih   = (const float*)d_in[10];
  const float* W_hh   = (const float*)d_in[11];
  const float* b_hh   = (const float*)d_in[12];
  const float* W_pd   = (const float*)d_in[13];
  const float* b_pd   = (const float*)d_in[14];
  const float* W_pld  = (const float*)d_in[15];
  const float* b_pld  = (const float*)d_in[16];
  const float* W_pq   = (const float*)d_in[17];
  const float* b_pq   = (const float*)d_in[18];
  const float* W_pr   = (const float*)d_in[19];
  const float* b_pr   = (const float*)d_in[20];
  const float* attn_W = (const float*)d_in[21];
  float* out = (float*)d_out;

  hipLaunchKernelGGL(drl4tsp_fused, dim3(NBLK), dim3(NT), 0, stream,
                     st, dyn, W_s, b_s, W_ld, b_ld, W_d, b_d, W_ih, b_ih,
                     W_hh, b_hh, W_pd, b_pd, W_pld, b_pld, W_pq, b_pq,
                     W_pr, b_pr, attn_W, mark, out);
}

// Round 14
// 2230.304 us; speedup vs baseline: 1.3686x; 1.0372x over previous
//
#include <hip/hip_runtime.h>

// DRL4TSP pointer-network decoder, fully fused single persistent kernel.
// R16: R15 failed absmax 5.0 (1-2 argmax flips, NOT divergence) -> the
// non-bit-exact changes (exp2-fold, tanh-sum refactor) perturbed the
// score path ~1e-6 and flipped a near-tie (+10000 mask => score ULP
// ~1e-3). The DPP row_half_mirror reduce is exonerated by the SMALL
// absmax (wrong reduces would diverge the LSTM -> absmax 100+).
// R16 = R14 base with only bit-exact-validated changes:
//  - Phase C: R14's exact fast_tanh math (bit-identical outputs).
//  - qsum8: xor4 ds_swizzle -> DPP 0x141 row_half_mirror (bit-exact:
//    quads uniform after xor1/xor2; same addends as xor4). Kills 40
//    LDS swizzles/step from reduce critical paths.
//  - A': R13's packed-v2f form (R13 PASSED with it; R14 dropped it only
//    for the jj-interleave pressure that no longer exists). Same FP
//    order per lane as dot4f -> bit-exact. 512 -> ~256 FMA-class ops.
// Structure unchanged: act |bar| B |bar| C |bar| (merge||A') |bar|.
//
// Key algebra (unchanged): with x[b,s] = (static0, static1, load-demand, demand):
//   static_hidden[b,h,s] = W_s[h,:].(x0,x1) + b_s[h]                 (rank-2)
//   base[b,h,s]          = A[h,:].x[b,s] + biasT[h]                  (rank-4)
//   dec@W_ih^T           = G[g,:].(x0,x1)[ptr] + gbias[g]            (rank-2)

#define H 128
#define S 128
#define NBATCH 2048
#define NB 8               // batch elements per block
#define NT 1024            // threads per block (16 waves, 4/SIMD)
#define NBLK (NBATCH / NB) // 256 blocks, 1/CU
#define BS (NBATCH * S)

// h-state LDS layout: quarter-swizzled, stride 36. 8-way 16-float K-slices
// land on 8 distinct bank-quads: conflict-free b128 reads (8-lane broadcast).
#define SHQ 36
#define SHB (4 * SHQ)
#define SHI(bb, h) ((bb) * SHB + (((h) >> 5) * SHQ) + ((h) & 31))
#define QPB 132            // qprime row stride (pad +4, rows 16B-aligned)
#define PADF 12288         // 48 KB pad: raw static LDS > 80 KB -> 1 WG/CU

typedef float v2f __attribute__((ext_vector_type(2)));
typedef float v4f __attribute__((ext_vector_type(4)));

__device__ __forceinline__ v2f fma2(v2f a, v2f b, v2f c) {
  return __builtin_elementwise_fma(a, b, c);
}
__device__ __forceinline__ v2f splat2(float x) { return (v2f){x, x}; }

__device__ __forceinline__ float dot4f(float4 a, float4 b, float c) {
  return fmaf(a.x, b.x, fmaf(a.y, b.y, fmaf(a.z, b.z, fmaf(a.w, b.w, c))));
}
__device__ __forceinline__ float fast_tanh(float x) {
  float e = __expf(2.f * x);
  float r = __builtin_amdgcn_rcpf(e + 1.f);
  return fmaf(-2.f, r, 1.f);
}
__device__ __forceinline__ float fast_sig(float x) {
  return __builtin_amdgcn_rcpf(1.f + __expf(-x));
}
// 8-lane sum, all-VALU: xor1/xor2 as DPP quad_perm; cross-quad merge as
// DPP row_half_mirror (0x141). After xor2 each quad is uniform, so
// half-mirror delivers the other quad's sum -> bit-identical to xor4.
__device__ __forceinline__ float qsum8(float a) {
  int t;
  t = __builtin_amdgcn_update_dpp(0, __float_as_int(a), 0xB1, 0xF, 0xF, true);
  a += __int_as_float(t);
  t = __builtin_amdgcn_update_dpp(0, __float_as_int(a), 0x4E, 0xF, 0xF, true);
  a += __int_as_float(t);
  t = __builtin_amdgcn_update_dpp(0, __float_as_int(a), 0x141, 0xF, 0xF, true);
  a += __int_as_float(t);
  return a;
}

__global__ __launch_bounds__(NT) __attribute__((amdgpu_waves_per_eu(4, 4)))
void drl4tsp_fused(const float* __restrict__ st, const float* __restrict__ dyn,
                   const float* __restrict__ W_s, const float* __restrict__ b_s,
                   const float* __restrict__ W_ld, const float* __restrict__ b_ld,
                   const float* __restrict__ W_d, const float* __restrict__ b_d,
                   const float* __restrict__ W_ih, const float* __restrict__ b_ih,
                   const float* __restrict__ W_hh, const float* __restrict__ b_hh,
                   const float* __restrict__ W_pd, const float* __restrict__ b_pd,
                   const float* __restrict__ W_pld, const float* __restrict__ b_pld,
                   const float* __restrict__ W_pq, const float* __restrict__ b_pq,
                   const float* __restrict__ W_pr, const float* __restrict__ b_pr,
                   const float* __restrict__ attn_W, const float* __restrict__ mark,
                   float* __restrict__ out)
{
  __shared__ float4 sX[NB][S];       // folded per-(b,s) inputs                16 KB
  __shared__ float4 sA[H];           // attention rank-4 weights                2 KB
  __shared__ alignas(16) float sAW[H];     // attn_W                          0.5 KB
  __shared__ float  sQB[H];          // biasT + b_pq                          0.5 KB
  __shared__ float4 sGT4[4][H];      // gate fold (gt0,gt1,gtb,-) per (g,h)     2 KB
  __shared__ float  sH[NB * SHB];    // h-state (single buffer)               4.5 KB
  __shared__ alignas(16) float sQP[NB * QPB]; // qprime = q + biasT             4 KB
  __shared__ float2 sPart[16][64];   // attn h-half partials per wave           8 KB
  __shared__ float  sOutI[NB][S];    // staged tour_idx                         4 KB
  __shared__ float  sOutL[NB][S];    // staged tour_logp                        4 KB
  __shared__ float  sSelX0[NB];
  __shared__ float  sSelX1[NB];
  __shared__ float  sPad[PADF];      // 48 KB occupancy governor

  const int tid = threadIdx.x;
  const int b0  = blockIdx.x * NB;
  const int gg  = tid >> 3, qq = tid & 7;    // matmul: h-row, 8-way K-split
  const int wv  = tid >> 6, lane = tid & 63; // attention
  const int cb  = wv & 7;                    // attention batch
  const int ch  = wv >> 3;                   // attention h-half (0/1)

  // Keep sPad allocated: VOLATILE store behind a runtime-opaque guard;
  // mark[0] == 0 in practice so it never executes.
  if (mark[0] > 1e30f) {
    volatile float* vp = sPad;
    vp[tid] = mark[0];
  }

  // ---------------- one-time fold tables & staging ----------------
  if (qq == 0) {
    #pragma unroll
    for (int g = 0; g < 4; ++g) {
      const int row = gg + g * H;
      const float* wr = W_ih + row * H;
      float g0 = 0.f, g1 = 0.f, gb = 0.f;
      for (int h = 0; h < H; h += 4) {
        float4 w   = *(const float4*)(wr + h);
        float4 s01 = *(const float4*)(W_s + 2 * h);
        float4 s23 = *(const float4*)(W_s + 2 * h + 4);
        float4 bs  = *(const float4*)(b_s + h);
        g0 = fmaf(w.x, s01.x, fmaf(w.y, s01.z, fmaf(w.z, s23.x, fmaf(w.w, s23.z, g0))));
        g1 = fmaf(w.x, s01.y, fmaf(w.y, s01.w, fmaf(w.z, s23.y, fmaf(w.w, s23.w, g1))));
        gb = fmaf(w.x, bs.x,  fmaf(w.y, bs.y,  fmaf(w.z, bs.z,  fmaf(w.w, bs.w,  gb))));
      }
      sGT4[g][gg] = make_float4(g0, g1, gb + b_ih[row] + b_hh[row], 0.f);
    }
  }
  if (tid < H) {
    const int h = tid;
    float a0 = 0.f, a1 = 0.f, a2 = 0.f, a3 = 0.f, bt = 0.f;
    for (int j = 0; j < H; ++j) {
      float pr  = W_pr[h * H + j];
      float pld = W_pld[h * H + j];
      float pd  = W_pd[h * H + j];
      float2 wsv = *(const float2*)(W_s + 2 * j);
      float2 wld = *(const float2*)(W_ld + 2 * j);
      float2 wd  = *(const float2*)(W_d + 2 * j);
      a0 = fmaf(pr, wsv.x, a0);
      a1 = fmaf(pr, wsv.y, a1);
      a2 = fmaf(pld, wld.x + wld.y, a2);
      a3 = fmaf(pd,  wd.x + wd.y,  a3);
      bt += pr * b_s[j] + pld * b_ld[j] + pd * b_d[j];
    }
    sA[h]  = make_float4(a0, a1, a2, a3);
    sAW[h] = attn_W[h];
    sQB[h] = bt + b_pr[h] + b_pld[h] + b_pd[h] + b_pq[h];
  }
  {
    int i = tid;                  // NB*S == NT: exactly one element each
    int bb = i >> 7, s = i & (S - 1);
    int go = (b0 + bb) * 2 * S;
    float x0 = st[go + s];
    float x1 = st[go + S + s];
    float ld = dyn[go + s];
    float dm = dyn[go + S + s];
    sX[bb][s] = make_float4(x0, x1, ld - dm, dm);
  }
  for (int i = tid; i < NB * SHB; i += NT) sH[i] = 0.f;
  if (tid < NB) {
    int go = (b0 + tid) * 2 * S;  // dec0 = static_hidden[:,:,0] -> x at s=0
    sSelX0[tid] = st[go + 0];
    sSelX1[tid] = st[go + S + 0];
  }
  if (blockIdx.x == 0 && tid == 0) out[2 * BS] = mark[0];

  // ---- register-resident weights: gate-PAIR interleaved 16-K slices ----
  // (R13's proven layout: {w_i,w_f} and {w_g,w_o} pairs; 64 regs total)
  v2f rW01[4][4], rW23[4][4];
  #pragma unroll
  for (int k = 0; k < 4; ++k) {
    const int co = 16 * qq + 4 * k;
    float4 w0 = *(const float4*)(W_hh + (gg        ) * H + co);
    float4 w1 = *(const float4*)(W_hh + (gg +     H) * H + co);
    float4 w2 = *(const float4*)(W_hh + (gg + 2 * H) * H + co);
    float4 w3 = *(const float4*)(W_hh + (gg + 3 * H) * H + co);
    rW01[k][0] = (v2f){w0.x, w1.x}; rW01[k][1] = (v2f){w0.y, w1.y};
    rW01[k][2] = (v2f){w0.z, w1.z}; rW01[k][3] = (v2f){w0.w, w1.w};
    rW23[k][0] = (v2f){w2.x, w3.x}; rW23[k][1] = (v2f){w2.y, w3.y};
    rW23[k][2] = (v2f){w2.z, w3.z}; rW23[k][3] = (v2f){w2.w, w3.w};
  }
  float4 rQ[4];                    // W_pq slice (16 regs)
  {
    const float* wr = W_pq + gg * H + 16 * qq;
    #pragma unroll
    for (int k = 0; k < 4; ++k) rQ[k] = *(const float4*)(wr + 4 * k);
  }
  __syncthreads();

  // ---------------- persistent per-thread setup ----------------
  const int ofsH = ((qq * 16) >> 5) * SHQ + ((qq * 16) & 31);
  const float qb = sQB[gg];
  // Phase C x-pairs: {xA.c, xB.c} packed once (step-invariant)
  v2f xx2, xy2, xz2, xw2;
  {
    float4 xA = sX[cb][lane];
    float4 xB = sX[cb][lane + 64];
    xx2 = (v2f){xA.x, xB.x}; xy2 = (v2f){xA.y, xB.y};
    xz2 = (v2f){xA.z, xB.z}; xw2 = (v2f){xA.w, xB.w};
  }
  float cS = 0.f;                      // c-state for (batch qq, h gg)
  float g4[4] = {0.f, 0.f, 0.f, 0.f};  // W_hh@h part of gates; h_{-1}=0 -> 0

  // ---------------- the 128-step decode scan ----------------
  // act |bar| B |bar| C |bar| (merge[wv<8] || A'[all]) |bar|
  #pragma unroll 1
  for (int t = 0; t < S; ++t) {
    // ---- act: gates = g4 + fold(x[sel]); h_t -> sH ----
    {
      const float x0p = sSelX0[qq], x1p = sSelX1[qq];
      float4 t0 = sGT4[0][gg];
      float4 t1 = sGT4[1][gg];
      float4 t2 = sGT4[2][gg];
      float4 t3 = sGT4[3][gg];
      float gi = g4[0] + fmaf(t0.x, x0p, fmaf(t0.y, x1p, t0.z));
      float gf = g4[1] + fmaf(t1.x, x0p, fmaf(t1.y, x1p, t1.z));
      float gc = g4[2] + fmaf(t2.x, x0p, fmaf(t2.y, x1p, t2.z));
      float go = g4[3] + fmaf(t3.x, x0p, fmaf(t3.y, x1p, t3.z));
      cS = fast_sig(gf) * cS + fast_sig(gi) * fast_tanh(gc);
      sH[SHI(qq, gg)] = fast_sig(go) * fast_tanh(cS);
    }
    __syncthreads();   // h_t visible

    // ---- Phase B: qprime = h_t @ W_pq^T + (b_pq + biasT) ----
    {
      float qval = 0.f;
      #pragma unroll
      for (int bb = 0; bb < NB; ++bb) {
        float qa = 0.f;
        const float* hp = &sH[bb * SHB + ofsH];
        #pragma unroll
        for (int k = 0; k < 4; ++k)
          qa = dot4f(rQ[k], *(const float4*)(hp + 4 * k), qa);
        qa = qsum8(qa);
        if (qq == bb) qval = qa + qb;
      }
      sQP[qq * QPB + gg] = qval;
    }
    __syncthreads();

    // ---- Phase C: attention (packed s/s+64), h in [64ch, 64ch+64) ----
    // Exactly R14's arithmetic (bit-identical outputs).
    v2f at2 = {0.f, 0.f};
    {
      const int hbase = 64 * ch;
      #pragma unroll 8
      for (int hh = 0; hh < 64; ++hh) {
        const int h = hbase + hh;
        float4 a  = sA[h];
        float  aw = sAW[h];
        float  q  = sQP[cb * QPB + h];
        v2f acc = splat2(q);
        acc = fma2(splat2(a.w), xw2, acc);
        acc = fma2(splat2(a.z), xz2, acc);
        acc = fma2(splat2(a.y), xy2, acc);
        acc = fma2(splat2(a.x), xx2, acc);
        v2f tt = acc + acc;                 // 2x (exact)
        v2f e  = (v2f){__expf(tt.x), __expf(tt.y)};
        v2f r  = (v2f){__builtin_amdgcn_rcpf(e.x + 1.f),
                       __builtin_amdgcn_rcpf(e.y + 1.f)};
        v2f th = fma2(splat2(-2.f), r, splat2(1.f));
        at2 = fma2(splat2(aw), th, at2);
      }
    }
    sPart[wv][lane] = make_float2(at2.x, at2.y);
    __syncthreads();

    // ---- merge (waves 0..7) || A' (all threads: gates for t+1) ----
    if (wv < 8) {
      float at0 = at2.x, at1 = at2.y;
      float2 o = sPart[wv ^ 8][lane];
      at0 += o.x; at1 += o.y;
      float a0v = at0 + ((lane == 0) ? 0.f : 10000.f);
      float a1v = at1 + 10000.f;
      float v; int idx;
      if (a1v > a0v) { v = a1v; idx = lane + 64; } else { v = a0v; idx = lane; }
      #pragma unroll
      for (int m = 1; m < 64; m <<= 1) {         // lexicographic max
        float ov = __shfl_xor(v, m);
        int   oi = __shfl_xor(idx, m);
        if (ov > v || (ov == v && oi < idx)) { v = ov; idx = oi; }
      }
      float es = __expf(a0v - v) + __expf(a1v - v);
      #pragma unroll
      for (int m = 1; m < 64; m <<= 1) es += __shfl_xor(es, m);
      if (lane == 0) {
        sOutI[cb][t] = (float)idx;               // staged tour_idx
        sOutL[cb][t] = -__logf(es);              // staged tour_logp
        float4 xv = sX[cb][idx];                 // dec_{t+1}
        sSelX0[cb] = xv.x;
        sSelX1[cb] = xv.y;
      }
    }
    // A': next step's W_hh @ h_t, packed gate-pairs (R13's proven form;
    // per-lane FP order identical to scalar dot4f: w,z,y,x within k).
    {
      #pragma unroll
      for (int bb = 0; bb < NB; ++bb) {
        v2f a01 = {0.f, 0.f}, a23 = {0.f, 0.f};
        const float* hp = &sH[bb * SHB + ofsH];
        #pragma unroll
        for (int k = 0; k < 4; ++k) {
          v4f hv = *(const v4f*)(hp + 4 * k);
          v2f hx = splat2(hv.x), hy = splat2(hv.y);
          v2f hz = splat2(hv.z), hw = splat2(hv.w);
          a01 = fma2(rW01[k][3], hw, a01);
          a01 = fma2(rW01[k][2], hz, a01);
          a01 = fma2(rW01[k][1], hy, a01);
          a01 = fma2(rW01[k][0], hx, a01);
          a23 = fma2(rW23[k][3], hw, a23);
          a23 = fma2(rW23[k][2], hz, a23);
          a23 = fma2(rW23[k][1], hy, a23);
          a23 = fma2(rW23[k][0], hx, a23);
        }
        float r0 = qsum8(a01.x);
        float r1 = qsum8(a01.y);
        float r2 = qsum8(a23.x);
        float r3 = qsum8(a23.y);
        if (qq == bb) { g4[0] = r0; g4[1] = r1; g4[2] = r2; g4[3] = r3; }
      }
    }
    __syncthreads();
  }

  // ---------------- bulk output flush (coalesced) ----------------
  {
    int bb = tid >> 7, s = tid & (S - 1);       // NB*S == NT
    const int bg = b0 + bb;
    out[bg * S + s]      = sOutI[bb][s];
    out[BS + bg * S + s] = sOutL[bb][s];
  }
}

extern "C" void kernel_launch(void* const* d_in, const int* in_sizes, int n_in,
                              void* d_out, int out_size, void* d_ws, size_t ws_size,
                              hipStream_t stream) {
  const float* st     = (const float*)d_in[0];
  const float* dyn    = (const float*)d_in[1];
  const float* mark   = (const float*)d_in[2];
  const float* W_s    = (const float*)d_in[3];
  const float* b_s    = (const float*)d_in[4];
  const float* W_ld   = (const float*)d_in[5];
  const float* b_ld   = (const float*)d_in[6];
  const float* W_d    = (const float*)d_in[7];
  const float* b_d    = (const float*)d_in[8];
  const float* W_ih   = (const float*)d_in[9];
  const float* b_ih   = (const float*)d_in[10];
  const float* W_hh   = (const float*)d_in[11];
  const float* b_hh   = (const float*)d_in[12];
  const float* W_pd   = (const float*)d_in[13];
  const float* b_pd   = (const float*)d_in[14];
  const float* W_pld  = (const float*)d_in[15];
  const float* b_pld  = (const float*)d_in[16];
  const float* W_pq   = (const float*)d_in[17];
  const float* b_pq   = (const float*)d_in[18];
  const float* W_pr   = (const float*)d_in[19];
  const float* b_pr   = (const float*)d_in[20];
  const float* attn_W = (const float*)d_in[21];
  float* out = (float*)d_out;

  hipLaunchKernelGGL(drl4tsp_fused, dim3(NBLK), dim3(NT), 0, stream,
                     st, dyn, W_s, b_s, W_ld, b_ld, W_d, b_d, W_ih, b_ih,
                     W_hh, b_hh, W_pd, b_pd, W_pld, b_pld, W_pq, b_pq,
                     W_pr, b_pr, attn_W, mark, out);
}

// Round 16
// 2178.213 us; speedup vs baseline: 1.4013x; 1.0239x over previous
//
#include <hip/hip_runtime.h>

// DRL4TSP pointer-network decoder, fully fused single persistent kernel.
// R18 == R17 resubmitted verbatim: the R17 bench died on infrastructure
// ("MI355X container failed twice") -- kernel never ran.
// R17: final safe polish on R16 (passed, steady ~2510, WRITE 12.3 MB).
// Both changes provably bit-exact (R15 lesson: score path is frozen --
// 1e-6 perturbation flips near-tie argmaxes):
//  1. Power-of-2 double-fold: sA/rQ/sQB pre-multiplied by 2. RN(2y) =
//     2*RN(y) exactly (exponent shift, no subnormals in range), so the
//     doubling distributes through every fma/add: acc arrives with
//     identical mantissa bits and __expf(acc) sees the SAME BITS as
//     R16's __expf(acc+acc). Deletes 64 pk_add/wave-step. sQP is only
//     consumed by C; B's butterfly sums scale exactly.
//  2. C's sAW/sQP reads vectorized to float4 chunks (every 4 iters,
//     both 16B-aligned: QPB=132 -> cb*528 = 33*16). ~96 fewer ds_read
//     issue slots/wave-step. FP order untouched.
// Structure unchanged: act |bar| B |bar| C |bar| (merge||A') |bar|.
// 4 barriers/step is provably minimal for this decomposition.
//
// Key algebra (unchanged): with x[b,s] = (static0, static1, load-demand, demand):
//   static_hidden[b,h,s] = W_s[h,:].(x0,x1) + b_s[h]                 (rank-2)
//   base[b,h,s]          = A[h,:].x[b,s] + biasT[h]                  (rank-4)
//   dec@W_ih^T           = G[g,:].(x0,x1)[ptr] + gbias[g]            (rank-2)

#define H 128
#define S 128
#define NBATCH 2048
#define NB 8               // batch elements per block
#define NT 1024            // threads per block (16 waves, 4/SIMD)
#define NBLK (NBATCH / NB) // 256 blocks, 1/CU
#define BS (NBATCH * S)

// h-state LDS layout: quarter-swizzled, stride 36. 8-way 16-float K-slices
// land on 8 distinct bank-quads: conflict-free b128 reads (8-lane broadcast).
#define SHQ 36
#define SHB (4 * SHQ)
#define SHI(bb, h) ((bb) * SHB + (((h) >> 5) * SHQ) + ((h) & 31))
#define QPB 132            // qprime row stride (pad +4, rows 16B-aligned)
#define PADF 12288         // 48 KB pad: raw static LDS > 80 KB -> 1 WG/CU

typedef float v2f __attribute__((ext_vector_type(2)));
typedef float v4f __attribute__((ext_vector_type(4)));

__device__ __forceinline__ v2f fma2(v2f a, v2f b, v2f c) {
  return __builtin_elementwise_fma(a, b, c);
}
__device__ __forceinline__ v2f splat2(float x) { return (v2f){x, x}; }

__device__ __forceinline__ float dot4f(float4 a, float4 b, float c) {
  return fmaf(a.x, b.x, fmaf(a.y, b.y, fmaf(a.z, b.z, fmaf(a.w, b.w, c))));
}
__device__ __forceinline__ float fast_tanh(float x) {
  float e = __expf(2.f * x);
  float r = __builtin_amdgcn_rcpf(e + 1.f);
  return fmaf(-2.f, r, 1.f);
}
__device__ __forceinline__ float fast_sig(float x) {
  return __builtin_amdgcn_rcpf(1.f + __expf(-x));
}
// 8-lane sum, all-VALU: xor1/xor2 as DPP quad_perm; cross-quad merge as
// DPP row_half_mirror (0x141). After xor2 each quad is uniform, so
// half-mirror delivers the other quad's sum -> bit-identical to xor4.
__device__ __forceinline__ float qsum8(float a) {
  int t;
  t = __builtin_amdgcn_update_dpp(0, __float_as_int(a), 0xB1, 0xF, 0xF, true);
  a += __int_as_float(t);
  t = __builtin_amdgcn_update_dpp(0, __float_as_int(a), 0x4E, 0xF, 0xF, true);
  a += __int_as_float(t);
  t = __builtin_amdgcn_update_dpp(0, __float_as_int(a), 0x141, 0xF, 0xF, true);
  a += __int_as_float(t);
  return a;
}

__global__ __launch_bounds__(NT) __attribute__((amdgpu_waves_per_eu(4, 4)))
void drl4tsp_fused(const float* __restrict__ st, const float* __restrict__ dyn,
                   const float* __restrict__ W_s, const float* __restrict__ b_s,
                   const float* __restrict__ W_ld, const float* __restrict__ b_ld,
                   const float* __restrict__ W_d, const float* __restrict__ b_d,
                   const float* __restrict__ W_ih, const float* __restrict__ b_ih,
                   const float* __restrict__ W_hh, const float* __restrict__ b_hh,
                   const float* __restrict__ W_pd, const float* __restrict__ b_pd,
                   const float* __restrict__ W_pld, const float* __restrict__ b_pld,
                   const float* __restrict__ W_pq, const float* __restrict__ b_pq,
                   const float* __restrict__ W_pr, const float* __restrict__ b_pr,
                   const float* __restrict__ attn_W, const float* __restrict__ mark,
                   float* __restrict__ out)
{
  __shared__ float4 sX[NB][S];       // folded per-(b,s) inputs                16 KB
  __shared__ float4 sA[H];           // attention rank-4 weights, 2x-scaled     2 KB
  __shared__ alignas(16) float sAW[H];     // attn_W                          0.5 KB
  __shared__ float  sQB[H];          // 2*(biasT + b_pq)                      0.5 KB
  __shared__ float4 sGT4[4][H];      // gate fold (gt0,gt1,gtb,-) per (g,h)     2 KB
  __shared__ float  sH[NB * SHB];    // h-state (single buffer)               4.5 KB
  __shared__ alignas(16) float sQP[NB * QPB]; // qprime, 2x-scaled              4 KB
  __shared__ float2 sPart[16][64];   // attn h-half partials per wave           8 KB
  __shared__ float  sOutI[NB][S];    // staged tour_idx                         4 KB
  __shared__ float  sOutL[NB][S];    // staged tour_logp                        4 KB
  __shared__ float  sSelX0[NB];
  __shared__ float  sSelX1[NB];
  __shared__ float  sPad[PADF];      // 48 KB occupancy governor

  const int tid = threadIdx.x;
  const int b0  = blockIdx.x * NB;
  const int gg  = tid >> 3, qq = tid & 7;    // matmul: h-row, 8-way K-split
  const int wv  = tid >> 6, lane = tid & 63; // attention
  const int cb  = wv & 7;                    // attention batch
  const int ch  = wv >> 3;                   // attention h-half (0/1)

  // Keep sPad allocated: VOLATILE store behind a runtime-opaque guard;
  // mark[0] == 0 in practice so it never executes.
  if (mark[0] > 1e30f) {
    volatile float* vp = sPad;
    vp[tid] = mark[0];
  }

  // ---------------- one-time fold tables & staging ----------------
  if (qq == 0) {
    #pragma unroll
    for (int g = 0; g < 4; ++g) {
      const int row = gg + g * H;
      const float* wr = W_ih + row * H;
      float g0 = 0.f, g1 = 0.f, gb = 0.f;
      for (int h = 0; h < H; h += 4) {
        float4 w   = *(const float4*)(wr + h);
        float4 s01 = *(const float4*)(W_s + 2 * h);
        float4 s23 = *(const float4*)(W_s + 2 * h + 4);
        float4 bs  = *(const float4*)(b_s + h);
        g0 = fmaf(w.x, s01.x, fmaf(w.y, s01.z, fmaf(w.z, s23.x, fmaf(w.w, s23.z, g0))));
        g1 = fmaf(w.x, s01.y, fmaf(w.y, s01.w, fmaf(w.z, s23.y, fmaf(w.w, s23.w, g1))));
        gb = fmaf(w.x, bs.x,  fmaf(w.y, bs.y,  fmaf(w.z, bs.z,  fmaf(w.w, bs.w,  gb))));
      }
      sGT4[g][gg] = make_float4(g0, g1, gb + b_ih[row] + b_hh[row], 0.f);
    }
  }
  if (tid < H) {
    const int h = tid;
    float a0 = 0.f, a1 = 0.f, a2 = 0.f, a3 = 0.f, bt = 0.f;
    for (int j = 0; j < H; ++j) {
      float pr  = W_pr[h * H + j];
      float pld = W_pld[h * H + j];
      float pd  = W_pd[h * H + j];
      float2 wsv = *(const float2*)(W_s + 2 * j);
      float2 wld = *(const float2*)(W_ld + 2 * j);
      float2 wd  = *(const float2*)(W_d + 2 * j);
      a0 = fmaf(pr, wsv.x, a0);
      a1 = fmaf(pr, wsv.y, a1);
      a2 = fmaf(pld, wld.x + wld.y, a2);
      a3 = fmaf(pd,  wd.x + wd.y,  a3);
      bt += pr * b_s[j] + pld * b_ld[j] + pd * b_d[j];
    }
    // 2x pre-scale (exact exponent shift): acc arrives pre-doubled so
    // __expf(acc) receives the same bits as __expf(acc+acc) before.
    sA[h]  = make_float4(2.f * a0, 2.f * a1, 2.f * a2, 2.f * a3);
    sAW[h] = attn_W[h];
    sQB[h] = 2.f * (bt + b_pr[h] + b_pld[h] + b_pd[h] + b_pq[h]);
  }
  {
    int i = tid;                  // NB*S == NT: exactly one element each
    int bb = i >> 7, s = i & (S - 1);
    int go = (b0 + bb) * 2 * S;
    float x0 = st[go + s];
    float x1 = st[go + S + s];
    float ld = dyn[go + s];
    float dm = dyn[go + S + s];
    sX[bb][s] = make_float4(x0, x1, ld - dm, dm);
  }
  for (int i = tid; i < NB * SHB; i += NT) sH[i] = 0.f;
  if (tid < NB) {
    int go = (b0 + tid) * 2 * S;  // dec0 = static_hidden[:,:,0] -> x at s=0
    sSelX0[tid] = st[go + 0];
    sSelX1[tid] = st[go + S + 0];
  }
  if (blockIdx.x == 0 && tid == 0) out[2 * BS] = mark[0];

  // ---- register-resident weights: gate-PAIR interleaved 16-K slices ----
  v2f rW01[4][4], rW23[4][4];
  #pragma unroll
  for (int k = 0; k < 4; ++k) {
    const int co = 16 * qq + 4 * k;
    float4 w0 = *(const float4*)(W_hh + (gg        ) * H + co);
    float4 w1 = *(const float4*)(W_hh + (gg +     H) * H + co);
    float4 w2 = *(const float4*)(W_hh + (gg + 2 * H) * H + co);
    float4 w3 = *(const float4*)(W_hh + (gg + 3 * H) * H + co);
    rW01[k][0] = (v2f){w0.x, w1.x}; rW01[k][1] = (v2f){w0.y, w1.y};
    rW01[k][2] = (v2f){w0.z, w1.z}; rW01[k][3] = (v2f){w0.w, w1.w};
    rW23[k][0] = (v2f){w2.x, w3.x}; rW23[k][1] = (v2f){w2.y, w3.y};
    rW23[k][2] = (v2f){w2.z, w3.z}; rW23[k][3] = (v2f){w2.w, w3.w};
  }
  float4 rQ[4];                    // W_pq slice, 2x-scaled (16 regs)
  {
    const float* wr = W_pq + gg * H + 16 * qq;
    #pragma unroll
    for (int k = 0; k < 4; ++k) {
      float4 w = *(const float4*)(wr + 4 * k);
      rQ[k] = make_float4(2.f * w.x, 2.f * w.y, 2.f * w.z, 2.f * w.w);
    }
  }
  __syncthreads();

  // ---------------- persistent per-thread setup ----------------
  const int ofsH = ((qq * 16) >> 5) * SHQ + ((qq * 16) & 31);
  const float qb = sQB[gg];
  // Phase C x-pairs: {xA.c, xB.c} packed once (step-invariant)
  v2f xx2, xy2, xz2, xw2;
  {
    float4 xA = sX[cb][lane];
    float4 xB = sX[cb][lane + 64];
    xx2 = (v2f){xA.x, xB.x}; xy2 = (v2f){xA.y, xB.y};
    xz2 = (v2f){xA.z, xB.z}; xw2 = (v2f){xA.w, xB.w};
  }
  float cS = 0.f;                      // c-state for (batch qq, h gg)
  float g4[4] = {0.f, 0.f, 0.f, 0.f};  // W_hh@h part of gates; h_{-1}=0 -> 0

  // ---------------- the 128-step decode scan ----------------
  // act |bar| B |bar| C |bar| (merge[wv<8] || A'[all]) |bar|
  #pragma unroll 1
  for (int t = 0; t < S; ++t) {
    // ---- act: gates = g4 + fold(x[sel]); h_t -> sH ----
    {
      const float x0p = sSelX0[qq], x1p = sSelX1[qq];
      float4 t0 = sGT4[0][gg];
      float4 t1 = sGT4[1][gg];
      float4 t2 = sGT4[2][gg];
      float4 t3 = sGT4[3][gg];
      float gi = g4[0] + fmaf(t0.x, x0p, fmaf(t0.y, x1p, t0.z));
      float gf = g4[1] + fmaf(t1.x, x0p, fmaf(t1.y, x1p, t1.z));
      float gc = g4[2] + fmaf(t2.x, x0p, fmaf(t2.y, x1p, t2.z));
      float go = g4[3] + fmaf(t3.x, x0p, fmaf(t3.y, x1p, t3.z));
      cS = fast_sig(gf) * cS + fast_sig(gi) * fast_tanh(gc);
      sH[SHI(qq, gg)] = fast_sig(go) * fast_tanh(cS);
    }
    __syncthreads();   // h_t visible

    // ---- Phase B: qprime = 2*(h_t @ W_pq^T + biasT + b_pq) ----
    // (rQ/qb pre-doubled: every fma/add scales exactly by 2)
    {
      float qval = 0.f;
      #pragma unroll
      for (int bb = 0; bb < NB; ++bb) {
        float qa = 0.f;
        const float* hp = &sH[bb * SHB + ofsH];
        #pragma unroll
        for (int k = 0; k < 4; ++k)
          qa = dot4f(rQ[k], *(const float4*)(hp + 4 * k), qa);
        qa = qsum8(qa);
        if (qq == bb) qval = qa + qb;
      }
      sQP[qq * QPB + gg] = qval;
    }
    __syncthreads();

    // ---- Phase C: attention (packed s/s+64), h in [64ch, 64ch+64) ----
    // acc pre-doubled -> __expf(acc) == R16's __expf(acc+acc), bit-exact.
    // sAW/sQP read as float4 chunks (pure read-width change).
    v2f at2 = {0.f, 0.f};
    {
      const int hbase = 64 * ch;
      #pragma unroll 2
      for (int h4 = 0; h4 < 16; ++h4) {
        const int h = hbase + 4 * h4;
        float4 aw4 = *(const float4*)(&sAW[h]);
        float4 q4  = *(const float4*)(&sQP[cb * QPB + h]);
        #pragma unroll
        for (int j = 0; j < 4; ++j) {
          float4 a  = sA[h + j];
          float  aw = (j == 0) ? aw4.x : (j == 1) ? aw4.y : (j == 2) ? aw4.z : aw4.w;
          float  q  = (j == 0) ? q4.x  : (j == 1) ? q4.y  : (j == 2) ? q4.z  : q4.w;
          v2f acc = splat2(q);
          acc = fma2(splat2(a.w), xw2, acc);
          acc = fma2(splat2(a.z), xz2, acc);
          acc = fma2(splat2(a.y), xy2, acc);
          acc = fma2(splat2(a.x), xx2, acc);
          v2f e  = (v2f){__expf(acc.x), __expf(acc.y)};
          v2f r  = (v2f){__builtin_amdgcn_rcpf(e.x + 1.f),
                         __builtin_amdgcn_rcpf(e.y + 1.f)};
          v2f th = fma2(splat2(-2.f), r, splat2(1.f));
          at2 = fma2(splat2(aw), th, at2);
        }
      }
    }
    sPart[wv][lane] = make_float2(at2.x, at2.y);
    __syncthreads();

    // ---- merge (waves 0..7) || A' (all threads: gates for t+1) ----
    if (wv < 8) {
      float at0 = at2.x, at1 = at2.y;
      float2 o = sPart[wv ^ 8][lane];
      at0 += o.x; at1 += o.y;
      float a0v = at0 + ((lane == 0) ? 0.f : 10000.f);
      float a1v = at1 + 10000.f;
      float v; int idx;
      if (a1v > a0v) { v = a1v; idx = lane + 64; } else { v = a0v; idx = lane; }
      #pragma unroll
      for (int m = 1; m < 64; m <<= 1) {         // lexicographic max
        float ov = __shfl_xor(v, m);
        int   oi = __shfl_xor(idx, m);
        if (ov > v || (ov == v && oi < idx)) { v = ov; idx = oi; }
      }
      float es = __expf(a0v - v) + __expf(a1v - v);
      #pragma unroll
      for (int m = 1; m < 64; m <<= 1) es += __shfl_xor(es, m);
      if (lane == 0) {
        sOutI[cb][t] = (float)idx;               // staged tour_idx
        sOutL[cb][t] = -__logf(es);              // staged tour_logp
        float4 xv = sX[cb][idx];                 // dec_{t+1}
        sSelX0[cb] = xv.x;
        sSelX1[cb] = xv.y;
      }
    }
    // A': next step's W_hh @ h_t, packed gate-pairs (per-lane FP order
    // identical to scalar dot4f: w,z,y,x within k; k ascending).
    {
      #pragma unroll
      for (int bb = 0; bb < NB; ++bb) {
        v2f a01 = {0.f, 0.f}, a23 = {0.f, 0.f};
        const float* hp = &sH[bb * SHB + ofsH];
        #pragma unroll
        for (int k = 0; k < 4; ++k) {
          v4f hv = *(const v4f*)(hp + 4 * k);
          v2f hx = splat2(hv.x), hy = splat2(hv.y);
          v2f hz = splat2(hv.z), hw = splat2(hv.w);
          a01 = fma2(rW01[k][3], hw, a01);
          a01 = fma2(rW01[k][2], hz, a01);
          a01 = fma2(rW01[k][1], hy, a01);
          a01 = fma2(rW01[k][0], hx, a01);
          a23 = fma2(rW23[k][3], hw, a23);
          a23 = fma2(rW23[k][2], hz, a23);
          a23 = fma2(rW23[k][1], hy, a23);
          a23 = fma2(rW23[k][0], hx, a23);
        }
        float r0 = qsum8(a01.x);
        float r1 = qsum8(a01.y);
        float r2 = qsum8(a23.x);
        float r3 = qsum8(a23.y);
        if (qq == bb) { g4[0] = r0; g4[1] = r1; g4[2] = r2; g4[3] = r3; }
      }
    }
    __syncthreads();
  }

  // ---------------- bulk output flush (coalesced) ----------------
  {
    int bb = tid >> 7, s = tid & (S - 1);       // NB*S == NT
    const int bg = b0 + bb;
    out[bg * S + s]      = sOutI[bb][s];
    out[BS + bg * S + s] = sOutL[bb][s];
  }
}

extern "C" void kernel_launch(void* const* d_in, const int* in_sizes, int n_in,
                              void* d_out, int out_size, void* d_ws, size_t ws_size,
                              hipStream_t stream) {
  const float* st     = (const float*)d_in[0];
  const float* dyn    = (const float*)d_in[1];
  const float* mark   = (const float*)d_in[2];
  const float* W_s    = (const float*)d_in[3];
  const float* b_s    = (const float*)d_in[4];
  const float* W_ld   = (const float*)d_in[5];
  const float* b_ld   = (const float*)d_in[6];
  const float* W_d    = (const float*)d_in[7];
  const float* b_d    = (const float*)d_in[8];
  const float* W_ih   = (const float*)d_in[9];
  const float* b_ih   = (const float*)d_in[10];
  const float* W_hh   = (const float*)d_in[11];
  const float* b_hh   = (const float*)d_in[12];
  const float* W_pd   = (const float*)d_in[13];
  const float* b_pd   = (const float*)d_in[14];
  const float* W_pld  = (const float*)d_in[15];
  const float* b_pld  = (const float*)d_in[16];
  const float* W_pq   = (const float*)d_in[17];
  const float* b_pq   = (const float*)d_in[18];
  const float* W_pr   = (const float*)d_in[19];
  const float* b_pr   = (const float*)d_in[20];
  const float* attn_W = (const float*)d_in[21];
  float* out = (float*)d_out;

  hipLaunchKernelGGL(drl4tsp_fused, dim3(NBLK), dim3(NT), 0, stream,
                     st, dyn, W_s, b_s, W_ld, b_ld, W_d, b_d, W_ih, b_ih,
                     W_hh, b_hh, W_pd, b_pd, W_pld, b_pld, W_pq, b_pq,
                     W_pr, b_pr, attn_W, mark, out);
}